// Round 4
// baseline (181.553 us; speedup 1.0000x reference)
//
#include <hip/hip_runtime.h>
#include <stdint.h>

typedef __attribute__((ext_vector_type(8))) short s16x8;
typedef __attribute__((ext_vector_type(4))) float f32x4;

#define MFMA16(a, b, c) __builtin_amdgcn_mfma_f32_16x16x32_bf16((a), (b), (c), 0, 0, 0)

// ---------- helpers ----------
__device__ __forceinline__ unsigned short f2bf(float f) {
    unsigned int u = __float_as_uint(f);
    return (unsigned short)((u + 0x7FFFu + ((u >> 16) & 1u)) >> 16);
}
__device__ __forceinline__ float bf2f(unsigned short h) {
    return __uint_as_float(((unsigned int)h) << 16);
}
__device__ __forceinline__ void cvt8(unsigned short* dst, const float* src) {
    const float4 f0 = *(const float4*)(src);
    const float4 f1 = *(const float4*)(src + 4);
    s16x8 v;
    v[0] = (short)f2bf(f0.x); v[1] = (short)f2bf(f0.y);
    v[2] = (short)f2bf(f0.z); v[3] = (short)f2bf(f0.w);
    v[4] = (short)f2bf(f1.x); v[5] = (short)f2bf(f1.y);
    v[6] = (short)f2bf(f1.z); v[7] = (short)f2bf(f1.w);
    *(s16x8*)dst = v;
}
// async global->LDS DMA, 16 B/lane; LDS base wave-uniform, lane i -> base+i*16.
__device__ __forceinline__ void gl_lds16(const unsigned short* g, unsigned short* l) {
    __builtin_amdgcn_global_load_lds(
        (const __attribute__((address_space(1))) unsigned int*)g,
        (__attribute__((address_space(3))) unsigned int*)l,
        16, 0, 0);
}

// ---------- merged fp32 -> bf16 convert for x / Wqkv / Wfc (one launch) ----------
__global__ __launch_bounds__(256) void cvt_all(const float* __restrict__ x,
                                               const float* __restrict__ wq,
                                               const float* __restrict__ wf,
                                               unsigned short* __restrict__ xb,
                                               unsigned short* __restrict__ wqb,
                                               unsigned short* __restrict__ wfb) {
    const int blk = blockIdx.x;  // 0..3135
    const float* src;
    unsigned short* dst;
    int base;
    if (blk < 2048)      { src = x;  dst = xb;  base = blk; }
    else if (blk < 2624) { src = wq; dst = wqb; base = blk - 2048; }
    else                 { src = wf; dst = wfb; base = blk - 2624; }
    const int i = (base * 256 + threadIdx.x) * 8;
    cvt8(&dst[i], &src[i]);
}

// ---------- GEMM 128(M)x64(N): r20 structure (unchanged this round) ----------
template <bool OUT_F32>
__global__ __launch_bounds__(512) void gemm_mn(const unsigned short* __restrict__ A,
                                               const unsigned short* __restrict__ Bw,
                                               void* __restrict__ Cout, int K, int N) {
    const int bm = blockIdx.x, bn = blockIdx.y;
    const int t = threadIdx.x;
    const int lane = t & 63, w = t >> 6;          // 8 waves
    const int quad = lane >> 4, col = lane & 15;
    const int wm = (w >> 1) * 32, wn = (w & 1) * 32;  // wave = 32x32

    __shared__ alignas(16) unsigned short As[2][128 * 64];  // 2 x 16 KB, swizzled
    __shared__ alignas(16) unsigned short Bs[2][64 * 64];   // 2 x  8 KB, swizzled

    f32x4 acc[2][2];
#pragma unroll
    for (int i = 0; i < 2; ++i)
#pragma unroll
        for (int j = 0; j < 2; ++j) acc[i][j] = (f32x4){0.f, 0.f, 0.f, 0.f};

    const int lrow = lane >> 3;                      // 0..7
    const int lcol = ((lane & 7) ^ lrow) * 8;        // swizzled global chunk
    // wave w stages A rows [w*16, w*16+16) (2 issues) and B rows [w*8, w*8+8)
    const unsigned short* Ap = A + (size_t)(bm * 128 + w * 16 + lrow) * K + lcol;
    const unsigned short* Bp = Bw + (size_t)(bn * 64 + w * 8 + lrow) * K + lcol;

    // prime tile 0 into buffer 0
#pragma unroll
    for (int j = 0; j < 2; ++j)
        gl_lds16(Ap + (size_t)(j * 8) * K, &As[0][(w * 16 + j * 8) * 64]);
    gl_lds16(Bp, &Bs[0][(w * 8) * 64]);
    __syncthreads();  // drain: tile 0 visible

    const int c7 = col & 7;
    const int fs0 = ((0 * 4 + quad) ^ c7) * 8;
    const int fs1 = ((1 * 4 + quad) ^ c7) * 8;

    for (int k0 = 0; k0 < K; k0 += 64) {
        const int p = (k0 >> 6) & 1;
        if (k0 + 64 < K) {  // stream next tile into the other buffer (no drain)
#pragma unroll
            for (int j = 0; j < 2; ++j)
                gl_lds16(Ap + (size_t)(j * 8) * K + k0 + 64, &As[p ^ 1][(w * 16 + j * 8) * 64]);
            gl_lds16(Bp + k0 + 64, &Bs[p ^ 1][(w * 8) * 64]);
        }
        // hoist ALL 8 fragment loads, then run the 8 MFMAs
        s16x8 af[2][2], bfr[2][2];
#pragma unroll
        for (int s = 0; s < 2; ++s) {
            const int fs = s ? fs1 : fs0;
#pragma unroll
            for (int i = 0; i < 2; ++i)
                af[s][i] = *(const s16x8*)&As[p][(wm + i * 16 + col) * 64 + fs];
#pragma unroll
            for (int j = 0; j < 2; ++j)
                bfr[s][j] = *(const s16x8*)&Bs[p][(wn + j * 16 + col) * 64 + fs];
        }
#pragma unroll
        for (int s = 0; s < 2; ++s)
#pragma unroll
            for (int i = 0; i < 2; ++i)
#pragma unroll
                for (int j = 0; j < 2; ++j)
                    acc[i][j] = MFMA16(af[s][i], bfr[s][j], acc[i][j]);
        __syncthreads();
    }
    const int rowb = bm * 128 + wm + quad * 4;
    const int colb = bn * 64 + wn + col;
#pragma unroll
    for (int i = 0; i < 2; ++i)
#pragma unroll
        for (int j = 0; j < 2; ++j)
#pragma unroll
            for (int r = 0; r < 4; ++r) {
                size_t off = (size_t)(rowb + i * 16 + r) * N + colb + j * 16;
                if (OUT_F32) ((float*)Cout)[off] = acc[i][j][r];
                else ((unsigned short*)Cout)[off] = f2bf(acc[i][j][r]);
            }
}

// ---------- LayerNorm over 1152, one WAVE per row (unchanged) ----------
__global__ __launch_bounds__(64) void ln_row(unsigned short* __restrict__ qkvn,
                                             const float* __restrict__ gamma,
                                             const float* __restrict__ beta,
                                             unsigned short* __restrict__ vT) {
    const int row = blockIdx.x;  // b*2048 + l
    const int b = row >> 11, l = row & 2047;
    unsigned short* rp = qkvn + (size_t)row * 1152;
    const int lane = threadIdx.x;

    s16x8 v0 = *(const s16x8*)&rp[lane * 8];
    s16x8 v1 = *(const s16x8*)&rp[512 + lane * 8];
    unsigned int v2u = *(const unsigned int*)&rp[1024 + lane * 2];

    float f0[8], f1[8], f2[2];
    float s = 0.f, s2 = 0.f;
#pragma unroll
    for (int e = 0; e < 8; ++e) {
        f0[e] = bf2f((unsigned short)v0[e]);
        f1[e] = bf2f((unsigned short)v1[e]);
        s += f0[e] + f1[e];
        s2 += f0[e] * f0[e] + f1[e] * f1[e];
    }
    f2[0] = bf2f((unsigned short)(v2u & 0xFFFF));
    f2[1] = bf2f((unsigned short)(v2u >> 16));
    s += f2[0] + f2[1];
    s2 += f2[0] * f2[0] + f2[1] * f2[1];

#pragma unroll
    for (int off = 1; off < 64; off <<= 1) {
        s += __shfl_xor(s, off);
        s2 += __shfl_xor(s2, off);
    }
    const float mu = s * (1.0f / 1152.0f);
    float var = s2 * (1.0f / 1152.0f) - mu * mu;
    var = fmaxf(var, 0.0f);
    const float rstd = rsqrtf(var + 1e-5f);

    {
        s16x8 o;
#pragma unroll
        for (int e = 0; e < 8; ++e)
            o[e] = (short)f2bf((f0[e] - mu) * rstd * gamma[lane * 8 + e] + beta[lane * 8 + e]);
        *(s16x8*)&rp[lane * 8] = o;
        if (lane >= 8 && lane < 16) {  // v head (cols 64..127) -> transposed copy
            const int d0 = lane * 8 - 64;
#pragma unroll
            for (int e = 0; e < 8; ++e)
                vT[((size_t)(b * 64 + d0 + e)) * 2048 + l] = (unsigned short)o[e];
        }
    }
    {
        s16x8 o;
#pragma unroll
        for (int e = 0; e < 8; ++e)
            o[e] = (short)f2bf((f1[e] - mu) * rstd * gamma[512 + lane * 8 + e] + beta[512 + lane * 8 + e]);
        *(s16x8*)&rp[512 + lane * 8] = o;
    }
    {
        unsigned short o0 = f2bf((f2[0] - mu) * rstd * gamma[1024 + lane * 2] + beta[1024 + lane * 2]);
        unsigned short o1 = f2bf((f2[1] - mu) * rstd * gamma[1025 + lane * 2] + beta[1025 + lane * 2]);
        *(unsigned int*)&rp[1024 + lane * 2] = ((unsigned int)o1 << 16) | o0;
    }
}

// ---------- Flash-style causal MQA — r21: BARRIER-FREE k-loop ----------
// Insight: K-head hot set = 2048x64 bf16 = 256 KB/batch; vT = 256 KB/batch.
// Both L2-resident -> LDS staging of K/V is pure overhead (catalog mistake #7),
// and it was the ONLY reason the k-loop had a barrier. Now Q/K/V fragments are
// read directly from global (L2-hit ~200cyc, issued early, hidden by 4 waves/
// SIMD); LDS holds only the per-wave P transpose buffer (no cross-wave hazard).
// ZERO barriers in the k-loop: waves free-run their causal prefix; the two
// remaining __syncthreads guard the epilogue k-split merge only.
__global__ __launch_bounds__(512, 4) void attn_kernel(const unsigned short* __restrict__ qkvn,
                                                      const unsigned short* __restrict__ vT,
                                                      unsigned short* __restrict__ obuf) {
    const int b = blockIdx.x >> 3, hp = blockIdx.x & 7;
    const int yy = blockIdx.y;
    const int qb = (yy < 16) ? (31 - yy) : (yy - 16);  // CU-paired: (31-a)+a = 33 iters/CU
    const int t = threadIdx.x;
    const int lane = t & 63, w = t >> 6;
    const int quad = lane >> 4, col = lane & 15;
    const int hl = w >> 2;              // head-local 0/1
    const int qhalf = (w >> 1) & 1;     // 32-q group within head
    const int kpar = w & 1;             // k-half of the 64-k tile

    // LDS: per-wave P [32][40] shorts (20480 B); epilogue reuses as merge slabs
    // (4 x 64x33 f32 = 33792 B + 4 x 32 f32 lm = 512 B).
    __shared__ alignas(16) unsigned char SM[34304];
    unsigned short* Ps = (unsigned short*)SM + w * 1280;  // per-wave [32][40]

    const int h = hp * 2 + hl;

    // Q fragments straight from global, pre-scaled by 1/8 (exact in bf16)
    s16x8 qfr[2][2];
#pragma unroll
    for (int qf = 0; qf < 2; ++qf)
#pragma unroll
        for (int dh = 0; dh < 2; ++dh) {
            const unsigned short* qsrc =
                qkvn + (size_t)(b * 2048 + qb * 64 + qhalf * 32 + qf * 16 + col) * 1152 +
                128 + h * 64 + dh * 32 + quad * 8;
            s16x8 v = *(const s16x8*)qsrc;
#pragma unroll
            for (int e = 0; e < 8; ++e)
                v[e] = (short)f2bf(bf2f((unsigned short)v[e]) * 0.125f);
            qfr[qf][dh] = v;
        }

    // per-lane global bases for K and V fragments
    // K[kglob = kb*64 + kpar*32 + nt*16 + col][d = dh*32 + quad*8 + e]
    const unsigned short* kbase0 =
        qkvn + (size_t)(b * 2048 + kpar * 32 + col) * 1152 + quad * 8;
    // V^T[d = ds*16 + col][k = kb*64 + kpar*32 + quad*8 + e]
    const unsigned short* vbase0 =
        vT + (size_t)(b * 64 + col) * 2048 + kpar * 32 + quad * 8;

    s16x8 ones;
#pragma unroll
    for (int e = 0; e < 8; ++e) ones[e] = (short)0x3F80;  // bf16 1.0

    f32x4 Oacc[4][2];     // [d-subtile][q-frag] of O^T[d][q]
    f32x4 lacc[2];        // [q-frag]
#pragma unroll
    for (int ds = 0; ds < 4; ++ds)
#pragma unroll
        for (int qf = 0; qf < 2; ++qf) Oacc[ds][qf] = (f32x4){0.f, 0.f, 0.f, 0.f};
    lacc[0] = (f32x4){0.f, 0.f, 0.f, 0.f};
    lacc[1] = (f32x4){0.f, 0.f, 0.f, 0.f};

    const int qbase = qb * 64 + qhalf * 32;   // + qf*16 + col = this lane's q rows

    for (int kb = 0; kb <= qb; ++kb) {
        const bool diag = (kb == qb);
        if (diag && kpar == 1 && qhalf == 0) break;  // fully-masked final sub-tile
        const bool needmask = diag && (kpar == qhalf);

        // V fragments: issue all 4 early, consumed at PV (whole QK+exp hides L2 latency)
        s16x8 vfr[4];
#pragma unroll
        for (int ds = 0; ds < 4; ++ds)
            vfr[ds] = *(const s16x8*)(vbase0 + (size_t)(ds * 16) * 2048 + kb * 64);

        // S^T = K (Q/8)^T for this wave's 32k x 32q -> mask -> exp -> P [q][k]
#pragma unroll
        for (int nt = 0; nt < 2; ++nt) {
            const unsigned short* krow = kbase0 + (size_t)(kb * 64 + nt * 16) * 1152;
            const s16x8 kf0 = *(const s16x8*)(krow);
            const s16x8 kf1 = *(const s16x8*)(krow + 32);
#pragma unroll
            for (int qf = 0; qf < 2; ++qf) {
                f32x4 z = (f32x4){-12.f, -12.f, -12.f, -12.f};  // exp bias via C-in
                z = MFMA16(kf0, qfr[qf][0], z);   // A=K, B=Q -> S^T[k][q] - 12
                z = MFMA16(kf1, qfr[qf][1], z);
                const int qg = qbase + qf * 16 + col;
                const int kl = kb * 64 + kpar * 32 + nt * 16 + quad * 4;
                float ev[4];
#pragma unroll
                for (int r = 0; r < 4; ++r) {
                    float sv = z[r];
                    if (needmask && (kl + r > qg)) sv = -1e30f;
                    ev[r] = __expf(sv);
                }
                unsigned int plo, phi;
                asm("v_cvt_pk_bf16_f32 %0, %1, %2" : "=v"(plo) : "v"(ev[0]), "v"(ev[1]));
                asm("v_cvt_pk_bf16_f32 %0, %1, %2" : "=v"(phi) : "v"(ev[2]), "v"(ev[3]));
                uint2 pk2;
                pk2.x = plo; pk2.y = phi;
                *(uint2*)&Ps[(qf * 16 + col) * 40 + nt * 16 + quad * 4] = pk2;  // 8B, k-contig
            }
        }

        const s16x8 pf0 = *(const s16x8*)&Ps[col * 40 + quad * 8];          // B: P[q][k]
        const s16x8 pf1 = *(const s16x8*)&Ps[(16 + col) * 40 + quad * 8];
        __builtin_amdgcn_s_setprio(1);
        lacc[0] = MFMA16(ones, pf0, lacc[0]);   // D[*][q] = partial l[q]
        lacc[1] = MFMA16(ones, pf1, lacc[1]);
#pragma unroll
        for (int ds = 0; ds < 4; ++ds) {
            Oacc[ds][0] = MFMA16(vfr[ds], pf0, Oacc[ds][0]);   // A=V^T, B=P^T -> O^T[d][q]
            Oacc[ds][1] = MFMA16(vfr[ds], pf1, Oacc[ds][1]);
        }
        __builtin_amdgcn_s_setprio(0);
    }

    // ---- epilogue: merge k-split partials of wave pair (w, w^1) through LDS ----
    __syncthreads();  // all waves done; P region dead -> reuse as merge slabs
    float* mg = (float*)SM + (hl * 2 + qhalf) * 2112;
    float* lm = (float*)(SM + 33792) + (hl * 2 + qhalf) * 32;
    if (kpar) {
#pragma unroll
        for (int ds = 0; ds < 4; ++ds)
#pragma unroll
            for (int qf = 0; qf < 2; ++qf)
#pragma unroll
                for (int r = 0; r < 4; ++r)
                    mg[(ds * 16 + quad * 4 + r) * 33 + qf * 16 + col] = Oacc[ds][qf][r];
        if (quad == 0) { lm[col] = lacc[0][0]; lm[16 + col] = lacc[1][0]; }
    }
    __syncthreads();
    if (!kpar) {
#pragma unroll
        for (int qf = 0; qf < 2; ++qf) {
            const int qglob = qbase + qf * 16 + col;
            const float inv = 1.0f / (lacc[qf][0] + lm[qf * 16 + col]);
            const size_t base = (((size_t)b * 2048 + qglob) * 16 + h) * 64 + quad * 4;
#pragma unroll
            for (int ds = 0; ds < 4; ++ds) {
                ushort4 ov;
                unsigned short* op = (unsigned short*)&ov;
#pragma unroll
                for (int r = 0; r < 4; ++r)
                    op[r] = f2bf((Oacc[ds][qf][r] + mg[(ds * 16 + quad * 4 + r) * 33 + qf * 16 + col]) * inv);
                *(ushort4*)&obuf[base + ds * 16] = ov;  // 8B packed store, d-contig
            }
        }
    }
}

// ---------- launch ----------
extern "C" void kernel_launch(void* const* d_in, const int* in_sizes, int n_in,
                              void* d_out, int out_size, void* d_ws, size_t ws_size,
                              hipStream_t stream) {
    (void)in_sizes; (void)n_in; (void)out_size; (void)ws_size;
    const float* x     = (const float*)d_in[0];  // (2,2048,1024) fp32
    const float* Wqkv  = (const float*)d_in[1];  // (1152,1024)  fp32
    const float* gamma = (const float*)d_in[2];  // (1152,)      fp32
    const float* beta  = (const float*)d_in[3];  // (1152,)      fp32
    const float* Wfc   = (const float*)d_in[4];  // (1024,1024)  fp32
    float* out = (float*)d_out;                  // (2,2048,1024) fp32

    // ws >= 22,806,528 B (proven in round 5)
    char* ws = (char*)d_ws;
    unsigned short* xb   = (unsigned short*)ws;               // 8,388,608
    unsigned short* Wqb  = (unsigned short*)(ws + 8388608);   // 2,359,296
    unsigned short* Wfb  = (unsigned short*)(ws + 10747904);  // 2,097,152
    unsigned short* qkvn = (unsigned short*)(ws + 12845056);  // 9,437,184
    unsigned short* vT   = (unsigned short*)(ws + 22282240);  //   524,288
    unsigned short* abuf = (unsigned short*)ws;               // alias xb (dead after gemm1)

    cvt_all<<<dim3(3136), 256, 0, stream>>>(x, Wqkv, Wfc, xb, Wqb, Wfb);
    gemm_mn<false><<<dim3(32, 18), 512, 0, stream>>>(xb, Wqb, qkvn, 1024, 1152);
    ln_row<<<dim3(4096), 64, 0, stream>>>(qkvn, gamma, beta, vT);
    attn_kernel<<<dim3(16, 32), 512, 0, stream>>>(qkvn, vT, abuf);
    gemm_mn<true><<<dim3(32, 16), 512, 0, stream>>>(abuf, Wfb, out, 1024, 1024);
}

// Round 5
// 149.026 us; speedup vs baseline: 1.2183x; 1.2183x over previous
//
#include <hip/hip_runtime.h>
#include <stdint.h>

typedef __attribute__((ext_vector_type(8))) short s16x8;
typedef __attribute__((ext_vector_type(4))) float f32x4;

#define MFMA16(a, b, c) __builtin_amdgcn_mfma_f32_16x16x32_bf16((a), (b), (c), 0, 0, 0)

// ---------- helpers ----------
__device__ __forceinline__ unsigned short f2bf(float f) {
    unsigned int u = __float_as_uint(f);
    return (unsigned short)((u + 0x7FFFu + ((u >> 16) & 1u)) >> 16);
}
__device__ __forceinline__ float bf2f(unsigned short h) {
    return __uint_as_float(((unsigned int)h) << 16);
}
__device__ __forceinline__ void cvt8(unsigned short* dst, const float* src) {
    const float4 f0 = *(const float4*)(src);
    const float4 f1 = *(const float4*)(src + 4);
    s16x8 v;
    v[0] = (short)f2bf(f0.x); v[1] = (short)f2bf(f0.y);
    v[2] = (short)f2bf(f0.z); v[3] = (short)f2bf(f0.w);
    v[4] = (short)f2bf(f1.x); v[5] = (short)f2bf(f1.y);
    v[6] = (short)f2bf(f1.z); v[7] = (short)f2bf(f1.w);
    *(s16x8*)dst = v;
}
// async global->LDS DMA, 16 B/lane; LDS base wave-uniform, lane i -> base+i*16.
__device__ __forceinline__ void gl_lds16(const unsigned short* g, unsigned short* l) {
    __builtin_amdgcn_global_load_lds(
        (const __attribute__((address_space(1))) unsigned int*)g,
        (__attribute__((address_space(3))) unsigned int*)l,
        16, 0, 0);
}

// ---------- merged fp32 -> bf16 convert for x / Wqkv / Wfc (one launch) ----------
__global__ __launch_bounds__(256) void cvt_all(const float* __restrict__ x,
                                               const float* __restrict__ wq,
                                               const float* __restrict__ wf,
                                               unsigned short* __restrict__ xb,
                                               unsigned short* __restrict__ wqb,
                                               unsigned short* __restrict__ wfb) {
    const int blk = blockIdx.x;  // 0..3135
    const float* src;
    unsigned short* dst;
    int base;
    if (blk < 2048)      { src = x;  dst = xb;  base = blk; }
    else if (blk < 2624) { src = wq; dst = wqb; base = blk - 2048; }
    else                 { src = wf; dst = wfb; base = blk - 2624; }
    const int i = (base * 256 + threadIdx.x) * 8;
    cvt8(&dst[i], &src[i]);
}

// ---------- GEMM r22: 128(M)x128(N) tile, 8 waves of 32x64, 64KB dbuf ----------
// r20's 128x64 tile ran ~2500cyc/iter vs ~1150 compute: the vmcnt(0) drain of
// the tile DMA (xb misses the 4MiB/XCD L2 -> ~900cyc L3 latency) is exposed per
// iter, and 576/512 blocks x 16 barriers couple everything. 128x128: DMA
// bytes/FLOP -33%, LDS reads/MFMA 1.0 -> 0.75, blocks and barrier-drain events
// halved (grids 32x9 / 32x8). Same swizzle (octet-conflict-free re-derived) and
// same issue->compute->barrier structure; launch_bounds(512,4) caps VGPR<=128
// so 64KB LDS keeps 2 blocks/CU co-resident for m114-style drain overlap.
template <bool OUT_F32>
__global__ __launch_bounds__(512, 4) void gemm_mn(const unsigned short* __restrict__ A,
                                                  const unsigned short* __restrict__ Bw,
                                                  void* __restrict__ Cout, int K, int N) {
    const int bm = blockIdx.x, bn = blockIdx.y;
    const int t = threadIdx.x;
    const int lane = t & 63, w = t >> 6;          // 8 waves
    const int quad = lane >> 4, col = lane & 15;
    const int wm = (w >> 1) * 32, wn = (w & 1) * 64;  // wave = 32(M) x 64(N)

    __shared__ alignas(16) unsigned short As[2][128 * 64];  // 2 x 16 KB, swizzled
    __shared__ alignas(16) unsigned short Bs[2][128 * 64];  // 2 x 16 KB, swizzled

    f32x4 acc[2][4];
#pragma unroll
    for (int i = 0; i < 2; ++i)
#pragma unroll
        for (int j = 0; j < 4; ++j) acc[i][j] = (f32x4){0.f, 0.f, 0.f, 0.f};

    const int lrow = lane >> 3;                      // 0..7
    const int lcol = ((lane & 7) ^ lrow) * 8;        // swizzled global chunk
    // wave w stages A rows [w*16, w*16+16) and B rows [w*16, w*16+16) (2 issues each)
    const unsigned short* Ap = A + (size_t)(bm * 128 + w * 16 + lrow) * K + lcol;
    const unsigned short* Bp = Bw + (size_t)(bn * 128 + w * 16 + lrow) * K + lcol;

    // prime tile 0 into buffer 0
#pragma unroll
    for (int j = 0; j < 2; ++j) {
        gl_lds16(Ap + (size_t)(j * 8) * K, &As[0][(w * 16 + j * 8) * 64]);
        gl_lds16(Bp + (size_t)(j * 8) * K, &Bs[0][(w * 16 + j * 8) * 64]);
    }
    __syncthreads();  // drain: tile 0 visible

    const int c7 = col & 7;
    const int fs0 = ((0 * 4 + quad) ^ c7) * 8;
    const int fs1 = ((1 * 4 + quad) ^ c7) * 8;

    for (int k0 = 0; k0 < K; k0 += 64) {
        const int p = (k0 >> 6) & 1;
        if (k0 + 64 < K) {  // stream next tile into the other buffer
#pragma unroll
            for (int j = 0; j < 2; ++j) {
                gl_lds16(Ap + (size_t)(j * 8) * K + k0 + 64, &As[p ^ 1][(w * 16 + j * 8) * 64]);
                gl_lds16(Bp + (size_t)(j * 8) * K + k0 + 64, &Bs[p ^ 1][(w * 16 + j * 8) * 64]);
            }
        }
        // hoist ALL 12 fragment loads, then run the 16 MFMAs
        s16x8 af[2][2], bfr[2][4];
#pragma unroll
        for (int s = 0; s < 2; ++s) {
            const int fs = s ? fs1 : fs0;
#pragma unroll
            for (int i = 0; i < 2; ++i)
                af[s][i] = *(const s16x8*)&As[p][(wm + i * 16 + col) * 64 + fs];
#pragma unroll
            for (int j = 0; j < 4; ++j)
                bfr[s][j] = *(const s16x8*)&Bs[p][(wn + j * 16 + col) * 64 + fs];
        }
#pragma unroll
        for (int s = 0; s < 2; ++s)
#pragma unroll
            for (int i = 0; i < 2; ++i)
#pragma unroll
                for (int j = 0; j < 4; ++j)
                    acc[i][j] = MFMA16(af[s][i], bfr[s][j], acc[i][j]);
        __syncthreads();
    }
    const int rowb = bm * 128 + wm + quad * 4;
    const int colb = bn * 128 + wn + col;
#pragma unroll
    for (int i = 0; i < 2; ++i)
#pragma unroll
        for (int j = 0; j < 4; ++j)
#pragma unroll
            for (int r = 0; r < 4; ++r) {
                size_t off = (size_t)(rowb + i * 16 + r) * N + colb + j * 16;
                if (OUT_F32) ((float*)Cout)[off] = acc[i][j][r];
                else ((unsigned short*)Cout)[off] = f2bf(acc[i][j][r]);
            }
}

// ---------- LayerNorm over 1152, one WAVE per row (unchanged) ----------
__global__ __launch_bounds__(64) void ln_row(unsigned short* __restrict__ qkvn,
                                             const float* __restrict__ gamma,
                                             const float* __restrict__ beta,
                                             unsigned short* __restrict__ vT) {
    const int row = blockIdx.x;  // b*2048 + l
    const int b = row >> 11, l = row & 2047;
    unsigned short* rp = qkvn + (size_t)row * 1152;
    const int lane = threadIdx.x;

    s16x8 v0 = *(const s16x8*)&rp[lane * 8];
    s16x8 v1 = *(const s16x8*)&rp[512 + lane * 8];
    unsigned int v2u = *(const unsigned int*)&rp[1024 + lane * 2];

    float f0[8], f1[8], f2[2];
    float s = 0.f, s2 = 0.f;
#pragma unroll
    for (int e = 0; e < 8; ++e) {
        f0[e] = bf2f((unsigned short)v0[e]);
        f1[e] = bf2f((unsigned short)v1[e]);
        s += f0[e] + f1[e];
        s2 += f0[e] * f0[e] + f1[e] * f1[e];
    }
    f2[0] = bf2f((unsigned short)(v2u & 0xFFFF));
    f2[1] = bf2f((unsigned short)(v2u >> 16));
    s += f2[0] + f2[1];
    s2 += f2[0] * f2[0] + f2[1] * f2[1];

#pragma unroll
    for (int off = 1; off < 64; off <<= 1) {
        s += __shfl_xor(s, off);
        s2 += __shfl_xor(s2, off);
    }
    const float mu = s * (1.0f / 1152.0f);
    float var = s2 * (1.0f / 1152.0f) - mu * mu;
    var = fmaxf(var, 0.0f);
    const float rstd = rsqrtf(var + 1e-5f);

    {
        s16x8 o;
#pragma unroll
        for (int e = 0; e < 8; ++e)
            o[e] = (short)f2bf((f0[e] - mu) * rstd * gamma[lane * 8 + e] + beta[lane * 8 + e]);
        *(s16x8*)&rp[lane * 8] = o;
        if (lane >= 8 && lane < 16) {  // v head (cols 64..127) -> transposed copy
            const int d0 = lane * 8 - 64;
#pragma unroll
            for (int e = 0; e < 8; ++e)
                vT[((size_t)(b * 64 + d0 + e)) * 2048 + l] = (unsigned short)o[e];
        }
    }
    {
        s16x8 o;
#pragma unroll
        for (int e = 0; e < 8; ++e)
            o[e] = (short)f2bf((f1[e] - mu) * rstd * gamma[512 + lane * 8 + e] + beta[512 + lane * 8 + e]);
        *(s16x8*)&rp[512 + lane * 8] = o;
    }
    {
        unsigned short o0 = f2bf((f2[0] - mu) * rstd * gamma[1024 + lane * 2] + beta[1024 + lane * 2]);
        unsigned short o1 = f2bf((f2[1] - mu) * rstd * gamma[1025 + lane * 2] + beta[1025 + lane * 2]);
        *(unsigned int*)&rp[1024 + lane * 2] = ((unsigned int)o1 << 16) | o0;
    }
}

// ---------- Flash-style causal MQA — r20 version (reverted: LDS staging + 1 barrier) ----------
// r21's barrier-free global-fragment variant measured 67.7us: K-frag reads were
// 16-cache-line gathers (row stride 2304B) -> MfmaUtil 10%, all pipes idle.
// LDS staging with coalesced DMA + one barrier/iter is strictly better.
__global__ __launch_bounds__(512, 4) void attn_kernel(const unsigned short* __restrict__ qkvn,
                                                      const unsigned short* __restrict__ vT,
                                                      unsigned short* __restrict__ obuf) {
    const int b = blockIdx.x >> 3, hp = blockIdx.x & 7;
    const int yy = blockIdx.y;
    const int qb = (yy < 16) ? (31 - yy) : (yy - 16);  // CU-paired: (31-a)+a = 33 iters/CU
    const int t = threadIdx.x;
    const int lane = t & 63, w = t >> 6;
    const int quad = lane >> 4, col = lane & 15;
    const int hl = w >> 2;              // head-local 0/1
    const int qhalf = (w >> 1) & 1;     // 32-q group within head
    const int kpar = w & 1;             // k-half of the 64-k tile

    __shared__ alignas(16) unsigned char SM[53248];
    unsigned short* Ks0 = (unsigned short*)SM;             // 8192 shorts
    unsigned short* Vt0 = (unsigned short*)(SM + 16384);   // 8192 shorts
    unsigned short* Qs  = (unsigned short*)(SM + 32768);   // [128][80] prologue view
    unsigned short* Ps  = (unsigned short*)(SM + 32768) + w * 1280;  // per-wave [32][40]

    const int srow = t >> 3;                  // 0..63
    const int schunk = t & 7;                 // global 8-short chunk
    const int ldsoff = srow * 64 + (schunk ^ (srow & 7)) * 8;  // swizzled LDS addr (shorts)

    // stage Q for both heads, pre-scaled by 1/8 (exact in bf16); stride 80 shorts
#pragma unroll
    for (int hh = 0; hh < 2; ++hh) {
        const unsigned short* qsrc =
            qkvn + (size_t)(b * 2048 + qb * 64 + srow) * 1152 + 128 + (hp * 2 + hh) * 64 + schunk * 8;
        s16x8 v = *(const s16x8*)qsrc;
#pragma unroll
        for (int e = 0; e < 8; ++e)
            v[e] = (short)f2bf(bf2f((unsigned short)v[e]) * 0.125f);
        *(s16x8*)&Qs[(hh * 64 + srow) * 80 + schunk * 8] = v;
    }
    __syncthreads();
    s16x8 qfr[2][2];
#pragma unroll
    for (int qf = 0; qf < 2; ++qf)
#pragma unroll
        for (int dh = 0; dh < 2; ++dh)
            qfr[qf][dh] = *(const s16x8*)&Qs[(hl * 64 + qhalf * 32 + qf * 16 + col) * 80 + dh * 32 + quad * 8];

    // stage K/V tile 0 (global reads linear; LDS writes swizzled)
    const unsigned short* kbase = qkvn + (size_t)(b * 2048 + srow) * 1152 + schunk * 8;  // + kb*64*1152
    const unsigned short* vbase = vT + (size_t)(b * 64 + srow) * 2048 + schunk * 8;      // + kb*64
    *(uint4*)&Ks0[ldsoff] = *(const uint4*)(kbase);
    *(uint4*)&Vt0[ldsoff] = *(const uint4*)(vbase);
    __syncthreads();  // KV0 visible; all Q-frag reads done -> PQ reusable as P

    const int c7 = col & 7;
    const int koff0 = (kpar * 32 + col) * 128 + ((quad ^ c7) * 16);
    const int koff1 = (kpar * 32 + col) * 128 + (((4 + quad) ^ c7) * 16);
    const int voff = col * 128 + (((kpar * 4 + quad) ^ c7) * 16);

    s16x8 ones;
#pragma unroll
    for (int e = 0; e < 8; ++e) ones[e] = (short)0x3F80;  // bf16 1.0

    f32x4 Oacc[4][2];     // [d-subtile][q-frag] of O^T[d][q]
    f32x4 lacc[2];        // [q-frag]
#pragma unroll
    for (int ds = 0; ds < 4; ++ds)
#pragma unroll
        for (int qf = 0; qf < 2; ++qf) Oacc[ds][qf] = (f32x4){0.f, 0.f, 0.f, 0.f};
    lacc[0] = (f32x4){0.f, 0.f, 0.f, 0.f};
    lacc[1] = (f32x4){0.f, 0.f, 0.f, 0.f};

    const int qbase = qb * 64 + qhalf * 32;   // + qf*16 + col = this lane's q rows

    for (int kb = 0; kb <= qb; ++kb) {
        const int p = kb & 1;
        uint4 kreg, vreg;
        if (kb < qb) {  // issue next tile's global loads before compute
            kreg = *(const uint4*)(kbase + (size_t)(kb + 1) * 64 * 1152);
            vreg = *(const uint4*)(vbase + (kb + 1) * 64);
        }
        const bool diag = (kb == qb);
        if (!(diag && kpar == 1 && qhalf == 0)) {
            const bool needmask = diag && (kpar == qhalf);
            const char* kb8 = (const char*)(Ks0 + p * 4096);
            const char* vb8 = (const char*)(Vt0 + p * 4096);

#pragma unroll
            for (int nt = 0; nt < 2; ++nt) {
                const s16x8 kf0 = *(const s16x8*)(kb8 + nt * 2048 + koff0);
                const s16x8 kf1 = *(const s16x8*)(kb8 + nt * 2048 + koff1);
#pragma unroll
                for (int qf = 0; qf < 2; ++qf) {
                    f32x4 z = (f32x4){-12.f, -12.f, -12.f, -12.f};  // exp bias via C-in
                    z = MFMA16(kf0, qfr[qf][0], z);   // A=K, B=Q -> S^T[k][q] - 12
                    z = MFMA16(kf1, qfr[qf][1], z);
                    const int qg = qbase + qf * 16 + col;
                    const int kl = kb * 64 + kpar * 32 + nt * 16 + quad * 4;
                    float ev[4];
#pragma unroll
                    for (int r = 0; r < 4; ++r) {
                        float sv = z[r];
                        if (needmask && (kl + r > qg)) sv = -1e30f;
                        ev[r] = __expf(sv);
                    }
                    unsigned int plo, phi;
                    asm("v_cvt_pk_bf16_f32 %0, %1, %2" : "=v"(plo) : "v"(ev[0]), "v"(ev[1]));
                    asm("v_cvt_pk_bf16_f32 %0, %1, %2" : "=v"(phi) : "v"(ev[2]), "v"(ev[3]));
                    uint2 pk2;
                    pk2.x = plo; pk2.y = phi;
                    *(uint2*)&Ps[(qf * 16 + col) * 40 + nt * 16 + quad * 4] = pk2;  // 8B, k-contig
                }
            }

            const s16x8 pf0 = *(const s16x8*)&Ps[col * 40 + quad * 8];          // B: P[q][k]
            const s16x8 pf1 = *(const s16x8*)&Ps[(16 + col) * 40 + quad * 8];
            __builtin_amdgcn_s_setprio(1);
            lacc[0] = MFMA16(ones, pf0, lacc[0]);   // D[*][q] = partial l[q]
            lacc[1] = MFMA16(ones, pf1, lacc[1]);
#pragma unroll
            for (int ds = 0; ds < 4; ++ds) {
                const s16x8 vf = *(const s16x8*)(vb8 + ds * 2048 + voff);
                Oacc[ds][0] = MFMA16(vf, pf0, Oacc[ds][0]);   // A=V^T, B=P^T -> O^T[d][q]
                Oacc[ds][1] = MFMA16(vf, pf1, Oacc[ds][1]);
            }
            __builtin_amdgcn_s_setprio(0);
        }

        if (kb < qb) {  // LDS-write prefetched tile into the other (swizzled) buffer
            *(uint4*)&Ks0[(p ^ 1) * 4096 + ldsoff] = kreg;
            *(uint4*)&Vt0[(p ^ 1) * 4096 + ldsoff] = vreg;
        }
        __syncthreads();  // ONE barrier per iter
    }

    // ---- epilogue: merge k-split partials of wave pair (w, w^1) through LDS ----
    float* mg = (float*)SM + (hl * 2 + qhalf) * 2112;
    float* lm = (float*)(SM + 33792) + (hl * 2 + qhalf) * 32;
    if (kpar) {
#pragma unroll
        for (int ds = 0; ds < 4; ++ds)
#pragma unroll
            for (int qf = 0; qf < 2; ++qf)
#pragma unroll
                for (int r = 0; r < 4; ++r)
                    mg[(ds * 16 + quad * 4 + r) * 33 + qf * 16 + col] = Oacc[ds][qf][r];
        if (quad == 0) { lm[col] = lacc[0][0]; lm[16 + col] = lacc[1][0]; }
    }
    __syncthreads();
    if (!kpar) {
        const int h = hp * 2 + hl;
#pragma unroll
        for (int qf = 0; qf < 2; ++qf) {
            const int qglob = qbase + qf * 16 + col;
            const float inv = 1.0f / (lacc[qf][0] + lm[qf * 16 + col]);
            const size_t base = (((size_t)b * 2048 + qglob) * 16 + h) * 64 + quad * 4;
#pragma unroll
            for (int ds = 0; ds < 4; ++ds) {
                ushort4 ov;
                unsigned short* op = (unsigned short*)&ov;
#pragma unroll
                for (int r = 0; r < 4; ++r)
                    op[r] = f2bf((Oacc[ds][qf][r] + mg[(ds * 16 + quad * 4 + r) * 33 + qf * 16 + col]) * inv);
                *(ushort4*)&obuf[base + ds * 16] = ov;  // 8B packed store, d-contig
            }
        }
    }
}

// ---------- launch ----------
extern "C" void kernel_launch(void* const* d_in, const int* in_sizes, int n_in,
                              void* d_out, int out_size, void* d_ws, size_t ws_size,
                              hipStream_t stream) {
    (void)in_sizes; (void)n_in; (void)out_size; (void)ws_size;
    const float* x     = (const float*)d_in[0];  // (2,2048,1024) fp32
    const float* Wqkv  = (const float*)d_in[1];  // (1152,1024)  fp32
    const float* gamma = (const float*)d_in[2];  // (1152,)      fp32
    const float* beta  = (const float*)d_in[3];  // (1152,)      fp32
    const float* Wfc   = (const float*)d_in[4];  // (1024,1024)  fp32
    float* out = (float*)d_out;                  // (2,2048,1024) fp32

    // ws >= 22,806,528 B (proven in round 5)
    char* ws = (char*)d_ws;
    unsigned short* xb   = (unsigned short*)ws;               // 8,388,608
    unsigned short* Wqb  = (unsigned short*)(ws + 8388608);   // 2,359,296
    unsigned short* Wfb  = (unsigned short*)(ws + 10747904);  // 2,097,152
    unsigned short* qkvn = (unsigned short*)(ws + 12845056);  // 9,437,184
    unsigned short* vT   = (unsigned short*)(ws + 22282240);  //   524,288
    unsigned short* abuf = (unsigned short*)ws;               // alias xb (dead after gemm1)

    cvt_all<<<dim3(3136), 256, 0, stream>>>(x, Wqkv, Wfc, xb, Wqb, Wfb);
    gemm_mn<false><<<dim3(32, 9), 512, 0, stream>>>(xb, Wqb, qkvn, 1024, 1152);
    ln_row<<<dim3(4096), 64, 0, stream>>>(qkvn, gamma, beta, vT);
    attn_kernel<<<dim3(16, 32), 512, 0, stream>>>(qkvn, vT, abuf);
    gemm_mn<true><<<dim3(32, 8), 512, 0, stream>>>(abuf, Wfb, out, 1024, 1024);
}

// Round 6
// 143.715 us; speedup vs baseline: 1.2633x; 1.0370x over previous
//
#include <hip/hip_runtime.h>
#include <stdint.h>

typedef __attribute__((ext_vector_type(8))) short s16x8;
typedef __attribute__((ext_vector_type(4))) float f32x4;

#define MFMA16(a, b, c) __builtin_amdgcn_mfma_f32_16x16x32_bf16((a), (b), (c), 0, 0, 0)

// ---------- helpers ----------
__device__ __forceinline__ unsigned short f2bf(float f) {
    unsigned int u = __float_as_uint(f);
    return (unsigned short)((u + 0x7FFFu + ((u >> 16) & 1u)) >> 16);
}
__device__ __forceinline__ float bf2f(unsigned short h) {
    return __uint_as_float(((unsigned int)h) << 16);
}
__device__ __forceinline__ void cvt8(unsigned short* dst, const float* src) {
    const float4 f0 = *(const float4*)(src);
    const float4 f1 = *(const float4*)(src + 4);
    s16x8 v;
    v[0] = (short)f2bf(f0.x); v[1] = (short)f2bf(f0.y);
    v[2] = (short)f2bf(f0.z); v[3] = (short)f2bf(f0.w);
    v[4] = (short)f2bf(f1.x); v[5] = (short)f2bf(f1.y);
    v[6] = (short)f2bf(f1.z); v[7] = (short)f2bf(f1.w);
    *(s16x8*)dst = v;
}
// async global->LDS DMA, 16 B/lane; LDS base wave-uniform, lane i -> base+i*16.
__device__ __forceinline__ void gl_lds16(const unsigned short* g, unsigned short* l) {
    __builtin_amdgcn_global_load_lds(
        (const __attribute__((address_space(1))) unsigned int*)g,
        (__attribute__((address_space(3))) unsigned int*)l,
        16, 0, 0);
}

// ---------- merged fp32 -> bf16 convert for x / Wqkv / Wfc (one launch) ----------
__global__ __launch_bounds__(256) void cvt_all(const float* __restrict__ x,
                                               const float* __restrict__ wq,
                                               const float* __restrict__ wf,
                                               unsigned short* __restrict__ xb,
                                               unsigned short* __restrict__ wqb,
                                               unsigned short* __restrict__ wfb) {
    const int blk = blockIdx.x;  // 0..3135
    const float* src;
    unsigned short* dst;
    int base;
    if (blk < 2048)      { src = x;  dst = xb;  base = blk; }
    else if (blk < 2624) { src = wq; dst = wqb; base = blk - 2048; }
    else                 { src = wf; dst = wfb; base = blk - 2624; }
    const int i = (base * 256 + threadIdx.x) * 8;
    cvt8(&dst[i], &src[i]);
}

// ---------- GEMM r23: r20 structure (128x64, 48KB, 3 blk/CU) + XCD-pinned decode ----------
// r22 (128x128, 2 blk/CU) regressed 145->149: makespan tail beat the DMA saving.
// Invariant cost identified: operand re-read stream. Linear dispatch scatters
// same-bm blocks over all 8 XCDs -> A re-reads (18x/9x) + B re-reads (32x) are
// served by L3 (~216 MB for gemm1), and the per-iter vmcnt(0) drain waits on
// L3/HBM latency (~600-900 cyc). Fix: HW maps wg -> XCD wg%8 (m09/T1), so
// decode bm = 4*xcd + (j&3), bn = j>>2: each XCD owns 4 A-panels (1 MB) x all
// bn, working set A(1MB)+B(2.36/2.0MB) < 4MiB L2 -> staging DMA L2-hits after
// first touch, drain latency ~200cyc. 72(64) blocks/XCD <= 96 slots: one round.
template <bool OUT_F32>
__global__ __launch_bounds__(512) void gemm_mn(const unsigned short* __restrict__ A,
                                               const unsigned short* __restrict__ Bw,
                                               void* __restrict__ Cout, int K, int N) {
    const int wg = blockIdx.x;
    const int xcd = wg & 7, j = wg >> 3;
    const int bm = (xcd << 2) + (j & 3);   // 4 A-panels per XCD
    const int bn = j >> 2;                 // all N-tiles per XCD
    const int t = threadIdx.x;
    const int lane = t & 63, w = t >> 6;          // 8 waves
    const int quad = lane >> 4, col = lane & 15;
    const int wm = (w >> 1) * 32, wn = (w & 1) * 32;  // wave = 32x32

    __shared__ alignas(16) unsigned short As[2][128 * 64];  // 2 x 16 KB, swizzled
    __shared__ alignas(16) unsigned short Bs[2][64 * 64];   // 2 x  8 KB, swizzled

    f32x4 acc[2][2];
#pragma unroll
    for (int i = 0; i < 2; ++i)
#pragma unroll
        for (int j2 = 0; j2 < 2; ++j2) acc[i][j2] = (f32x4){0.f, 0.f, 0.f, 0.f};

    const int lrow = lane >> 3;                      // 0..7
    const int lcol = ((lane & 7) ^ lrow) * 8;        // swizzled global chunk
    // wave w stages A rows [w*16, w*16+16) (2 issues) and B rows [w*8, w*8+8)
    const unsigned short* Ap = A + (size_t)(bm * 128 + w * 16 + lrow) * K + lcol;
    const unsigned short* Bp = Bw + (size_t)(bn * 64 + w * 8 + lrow) * K + lcol;

    // prime tile 0 into buffer 0
#pragma unroll
    for (int j2 = 0; j2 < 2; ++j2)
        gl_lds16(Ap + (size_t)(j2 * 8) * K, &As[0][(w * 16 + j2 * 8) * 64]);
    gl_lds16(Bp, &Bs[0][(w * 8) * 64]);
    __syncthreads();  // drain: tile 0 visible

    const int c7 = col & 7;
    const int fs0 = ((0 * 4 + quad) ^ c7) * 8;
    const int fs1 = ((1 * 4 + quad) ^ c7) * 8;

    for (int k0 = 0; k0 < K; k0 += 64) {
        const int p = (k0 >> 6) & 1;
        if (k0 + 64 < K) {  // stream next tile into the other buffer (no drain)
#pragma unroll
            for (int j2 = 0; j2 < 2; ++j2)
                gl_lds16(Ap + (size_t)(j2 * 8) * K + k0 + 64, &As[p ^ 1][(w * 16 + j2 * 8) * 64]);
            gl_lds16(Bp + k0 + 64, &Bs[p ^ 1][(w * 8) * 64]);
        }
        // hoist ALL 8 fragment loads, then run the 8 MFMAs
        s16x8 af[2][2], bfr[2][2];
#pragma unroll
        for (int s = 0; s < 2; ++s) {
            const int fs = s ? fs1 : fs0;
#pragma unroll
            for (int i = 0; i < 2; ++i)
                af[s][i] = *(const s16x8*)&As[p][(wm + i * 16 + col) * 64 + fs];
#pragma unroll
            for (int j2 = 0; j2 < 2; ++j2)
                bfr[s][j2] = *(const s16x8*)&Bs[p][(wn + j2 * 16 + col) * 64 + fs];
        }
#pragma unroll
        for (int s = 0; s < 2; ++s)
#pragma unroll
            for (int i = 0; i < 2; ++i)
#pragma unroll
                for (int j2 = 0; j2 < 2; ++j2)
                    acc[i][j2] = MFMA16(af[s][i], bfr[s][j2], acc[i][j2]);
        __syncthreads();
    }
    const int rowb = bm * 128 + wm + quad * 4;
    const int colb = bn * 64 + wn + col;
#pragma unroll
    for (int i = 0; i < 2; ++i)
#pragma unroll
        for (int j2 = 0; j2 < 2; ++j2)
#pragma unroll
            for (int r = 0; r < 4; ++r) {
                size_t off = (size_t)(rowb + i * 16 + r) * N + colb + j2 * 16;
                if (OUT_F32) ((float*)Cout)[off] = acc[i][j2][r];
                else ((unsigned short*)Cout)[off] = f2bf(acc[i][j2][r]);
            }
}

// ---------- LayerNorm over 1152, one WAVE per row (unchanged) ----------
__global__ __launch_bounds__(64) void ln_row(unsigned short* __restrict__ qkvn,
                                             const float* __restrict__ gamma,
                                             const float* __restrict__ beta,
                                             unsigned short* __restrict__ vT) {
    const int row = blockIdx.x;  // b*2048 + l
    const int b = row >> 11, l = row & 2047;
    unsigned short* rp = qkvn + (size_t)row * 1152;
    const int lane = threadIdx.x;

    s16x8 v0 = *(const s16x8*)&rp[lane * 8];
    s16x8 v1 = *(const s16x8*)&rp[512 + lane * 8];
    unsigned int v2u = *(const unsigned int*)&rp[1024 + lane * 2];

    float f0[8], f1[8], f2[2];
    float s = 0.f, s2 = 0.f;
#pragma unroll
    for (int e = 0; e < 8; ++e) {
        f0[e] = bf2f((unsigned short)v0[e]);
        f1[e] = bf2f((unsigned short)v1[e]);
        s += f0[e] + f1[e];
        s2 += f0[e] * f0[e] + f1[e] * f1[e];
    }
    f2[0] = bf2f((unsigned short)(v2u & 0xFFFF));
    f2[1] = bf2f((unsigned short)(v2u >> 16));
    s += f2[0] + f2[1];
    s2 += f2[0] * f2[0] + f2[1] * f2[1];

#pragma unroll
    for (int off = 1; off < 64; off <<= 1) {
        s += __shfl_xor(s, off);
        s2 += __shfl_xor(s2, off);
    }
    const float mu = s * (1.0f / 1152.0f);
    float var = s2 * (1.0f / 1152.0f) - mu * mu;
    var = fmaxf(var, 0.0f);
    const float rstd = rsqrtf(var + 1e-5f);

    {
        s16x8 o;
#pragma unroll
        for (int e = 0; e < 8; ++e)
            o[e] = (short)f2bf((f0[e] - mu) * rstd * gamma[lane * 8 + e] + beta[lane * 8 + e]);
        *(s16x8*)&rp[lane * 8] = o;
        if (lane >= 8 && lane < 16) {  // v head (cols 64..127) -> transposed copy
            const int d0 = lane * 8 - 64;
#pragma unroll
            for (int e = 0; e < 8; ++e)
                vT[((size_t)(b * 64 + d0 + e)) * 2048 + l] = (unsigned short)o[e];
        }
    }
    {
        s16x8 o;
#pragma unroll
        for (int e = 0; e < 8; ++e)
            o[e] = (short)f2bf((f1[e] - mu) * rstd * gamma[512 + lane * 8 + e] + beta[512 + lane * 8 + e]);
        *(s16x8*)&rp[512 + lane * 8] = o;
    }
    {
        unsigned short o0 = f2bf((f2[0] - mu) * rstd * gamma[1024 + lane * 2] + beta[1024 + lane * 2]);
        unsigned short o1 = f2bf((f2[1] - mu) * rstd * gamma[1025 + lane * 2] + beta[1025 + lane * 2]);
        *(unsigned int*)&rp[1024 + lane * 2] = ((unsigned int)o1 << 16) | o0;
    }
}

// ---------- Flash-style causal MQA — r20 version (LDS staging + 1 barrier) ----------
__global__ __launch_bounds__(512, 4) void attn_kernel(const unsigned short* __restrict__ qkvn,
                                                      const unsigned short* __restrict__ vT,
                                                      unsigned short* __restrict__ obuf) {
    const int b = blockIdx.x >> 3, hp = blockIdx.x & 7;
    const int yy = blockIdx.y;
    const int qb = (yy < 16) ? (31 - yy) : (yy - 16);  // CU-paired: (31-a)+a = 33 iters/CU
    const int t = threadIdx.x;
    const int lane = t & 63, w = t >> 6;
    const int quad = lane >> 4, col = lane & 15;
    const int hl = w >> 2;              // head-local 0/1
    const int qhalf = (w >> 1) & 1;     // 32-q group within head
    const int kpar = w & 1;             // k-half of the 64-k tile

    __shared__ alignas(16) unsigned char SM[53248];
    unsigned short* Ks0 = (unsigned short*)SM;             // 8192 shorts
    unsigned short* Vt0 = (unsigned short*)(SM + 16384);   // 8192 shorts
    unsigned short* Qs  = (unsigned short*)(SM + 32768);   // [128][80] prologue view
    unsigned short* Ps  = (unsigned short*)(SM + 32768) + w * 1280;  // per-wave [32][40]

    const int srow = t >> 3;                  // 0..63
    const int schunk = t & 7;                 // global 8-short chunk
    const int ldsoff = srow * 64 + (schunk ^ (srow & 7)) * 8;  // swizzled LDS addr (shorts)

    // stage Q for both heads, pre-scaled by 1/8 (exact in bf16); stride 80 shorts
#pragma unroll
    for (int hh = 0; hh < 2; ++hh) {
        const unsigned short* qsrc =
            qkvn + (size_t)(b * 2048 + qb * 64 + srow) * 1152 + 128 + (hp * 2 + hh) * 64 + schunk * 8;
        s16x8 v = *(const s16x8*)qsrc;
#pragma unroll
        for (int e = 0; e < 8; ++e)
            v[e] = (short)f2bf(bf2f((unsigned short)v[e]) * 0.125f);
        *(s16x8*)&Qs[(hh * 64 + srow) * 80 + schunk * 8] = v;
    }
    __syncthreads();
    s16x8 qfr[2][2];
#pragma unroll
    for (int qf = 0; qf < 2; ++qf)
#pragma unroll
        for (int dh = 0; dh < 2; ++dh)
            qfr[qf][dh] = *(const s16x8*)&Qs[(hl * 64 + qhalf * 32 + qf * 16 + col) * 80 + dh * 32 + quad * 8];

    // stage K/V tile 0 (global reads linear; LDS writes swizzled)
    const unsigned short* kbase = qkvn + (size_t)(b * 2048 + srow) * 1152 + schunk * 8;  // + kb*64*1152
    const unsigned short* vbase = vT + (size_t)(b * 64 + srow) * 2048 + schunk * 8;      // + kb*64
    *(uint4*)&Ks0[ldsoff] = *(const uint4*)(kbase);
    *(uint4*)&Vt0[ldsoff] = *(const uint4*)(vbase);
    __syncthreads();  // KV0 visible; all Q-frag reads done -> PQ reusable as P

    const int c7 = col & 7;
    const int koff0 = (kpar * 32 + col) * 128 + ((quad ^ c7) * 16);
    const int koff1 = (kpar * 32 + col) * 128 + (((4 + quad) ^ c7) * 16);
    const int voff = col * 128 + (((kpar * 4 + quad) ^ c7) * 16);

    s16x8 ones;
#pragma unroll
    for (int e = 0; e < 8; ++e) ones[e] = (short)0x3F80;  // bf16 1.0

    f32x4 Oacc[4][2];     // [d-subtile][q-frag] of O^T[d][q]
    f32x4 lacc[2];        // [q-frag]
#pragma unroll
    for (int ds = 0; ds < 4; ++ds)
#pragma unroll
        for (int qf = 0; qf < 2; ++qf) Oacc[ds][qf] = (f32x4){0.f, 0.f, 0.f, 0.f};
    lacc[0] = (f32x4){0.f, 0.f, 0.f, 0.f};
    lacc[1] = (f32x4){0.f, 0.f, 0.f, 0.f};

    const int qbase = qb * 64 + qhalf * 32;   // + qf*16 + col = this lane's q rows

    for (int kb = 0; kb <= qb; ++kb) {
        const int p = kb & 1;
        uint4 kreg, vreg;
        if (kb < qb) {  // issue next tile's global loads before compute
            kreg = *(const uint4*)(kbase + (size_t)(kb + 1) * 64 * 1152);
            vreg = *(const uint4*)(vbase + (kb + 1) * 64);
        }
        const bool diag = (kb == qb);
        if (!(diag && kpar == 1 && qhalf == 0)) {
            const bool needmask = diag && (kpar == qhalf);
            const char* kb8 = (const char*)(Ks0 + p * 4096);
            const char* vb8 = (const char*)(Vt0 + p * 4096);

#pragma unroll
            for (int nt = 0; nt < 2; ++nt) {
                const s16x8 kf0 = *(const s16x8*)(kb8 + nt * 2048 + koff0);
                const s16x8 kf1 = *(const s16x8*)(kb8 + nt * 2048 + koff1);
#pragma unroll
                for (int qf = 0; qf < 2; ++qf) {
                    f32x4 z = (f32x4){-12.f, -12.f, -12.f, -12.f};  // exp bias via C-in
                    z = MFMA16(kf0, qfr[qf][0], z);   // A=K, B=Q -> S^T[k][q] - 12
                    z = MFMA16(kf1, qfr[qf][1], z);
                    const int qg = qbase + qf * 16 + col;
                    const int kl = kb * 64 + kpar * 32 + nt * 16 + quad * 4;
                    float ev[4];
#pragma unroll
                    for (int r = 0; r < 4; ++r) {
                        float sv = z[r];
                        if (needmask && (kl + r > qg)) sv = -1e30f;
                        ev[r] = __expf(sv);
                    }
                    unsigned int plo, phi;
                    asm("v_cvt_pk_bf16_f32 %0, %1, %2" : "=v"(plo) : "v"(ev[0]), "v"(ev[1]));
                    asm("v_cvt_pk_bf16_f32 %0, %1, %2" : "=v"(phi) : "v"(ev[2]), "v"(ev[3]));
                    uint2 pk2;
                    pk2.x = plo; pk2.y = phi;
                    *(uint2*)&Ps[(qf * 16 + col) * 40 + nt * 16 + quad * 4] = pk2;  // 8B, k-contig
                }
            }

            const s16x8 pf0 = *(const s16x8*)&Ps[col * 40 + quad * 8];          // B: P[q][k]
            const s16x8 pf1 = *(const s16x8*)&Ps[(16 + col) * 40 + quad * 8];
            __builtin_amdgcn_s_setprio(1);
            lacc[0] = MFMA16(ones, pf0, lacc[0]);   // D[*][q] = partial l[q]
            lacc[1] = MFMA16(ones, pf1, lacc[1]);
#pragma unroll
            for (int ds = 0; ds < 4; ++ds) {
                const s16x8 vf = *(const s16x8*)(vb8 + ds * 2048 + voff);
                Oacc[ds][0] = MFMA16(vf, pf0, Oacc[ds][0]);   // A=V^T, B=P^T -> O^T[d][q]
                Oacc[ds][1] = MFMA16(vf, pf1, Oacc[ds][1]);
            }
            __builtin_amdgcn_s_setprio(0);
        }

        if (kb < qb) {  // LDS-write prefetched tile into the other (swizzled) buffer
            *(uint4*)&Ks0[(p ^ 1) * 4096 + ldsoff] = kreg;
            *(uint4*)&Vt0[(p ^ 1) * 4096 + ldsoff] = vreg;
        }
        __syncthreads();  // ONE barrier per iter
    }

    // ---- epilogue: merge k-split partials of wave pair (w, w^1) through LDS ----
    float* mg = (float*)SM + (hl * 2 + qhalf) * 2112;
    float* lm = (float*)(SM + 33792) + (hl * 2 + qhalf) * 32;
    if (kpar) {
#pragma unroll
        for (int ds = 0; ds < 4; ++ds)
#pragma unroll
            for (int qf = 0; qf < 2; ++qf)
#pragma unroll
                for (int r = 0; r < 4; ++r)
                    mg[(ds * 16 + quad * 4 + r) * 33 + qf * 16 + col] = Oacc[ds][qf][r];
        if (quad == 0) { lm[col] = lacc[0][0]; lm[16 + col] = lacc[1][0]; }
    }
    __syncthreads();
    if (!kpar) {
        const int h = hp * 2 + hl;
#pragma unroll
        for (int qf = 0; qf < 2; ++qf) {
            const int qglob = qbase + qf * 16 + col;
            const float inv = 1.0f / (lacc[qf][0] + lm[qf * 16 + col]);
            const size_t base = (((size_t)b * 2048 + qglob) * 16 + h) * 64 + quad * 4;
#pragma unroll
            for (int ds = 0; ds < 4; ++ds) {
                ushort4 ov;
                unsigned short* op = (unsigned short*)&ov;
#pragma unroll
                for (int r = 0; r < 4; ++r)
                    op[r] = f2bf((Oacc[ds][qf][r] + mg[(ds * 16 + quad * 4 + r) * 33 + qf * 16 + col]) * inv);
                *(ushort4*)&obuf[base + ds * 16] = ov;  // 8B packed store, d-contig
            }
        }
    }
}

// ---------- launch ----------
extern "C" void kernel_launch(void* const* d_in, const int* in_sizes, int n_in,
                              void* d_out, int out_size, void* d_ws, size_t ws_size,
                              hipStream_t stream) {
    (void)in_sizes; (void)n_in; (void)out_size; (void)ws_size;
    const float* x     = (const float*)d_in[0];  // (2,2048,1024) fp32
    const float* Wqkv  = (const float*)d_in[1];  // (1152,1024)  fp32
    const float* gamma = (const float*)d_in[2];  // (1152,)      fp32
    const float* beta  = (const float*)d_in[3];  // (1152,)      fp32
    const float* Wfc   = (const float*)d_in[4];  // (1024,1024)  fp32
    float* out = (float*)d_out;                  // (2,2048,1024) fp32

    // ws >= 22,806,528 B (proven in round 5)
    char* ws = (char*)d_ws;
    unsigned short* xb   = (unsigned short*)ws;               // 8,388,608
    unsigned short* Wqb  = (unsigned short*)(ws + 8388608);   // 2,359,296
    unsigned short* Wfb  = (unsigned short*)(ws + 10747904);  // 2,097,152
    unsigned short* qkvn = (unsigned short*)(ws + 12845056);  // 9,437,184
    unsigned short* vT   = (unsigned short*)(ws + 22282240);  //   524,288
    unsigned short* abuf = (unsigned short*)ws;               // alias xb (dead after gemm1)

    cvt_all<<<dim3(3136), 256, 0, stream>>>(x, Wqkv, Wfc, xb, Wqb, Wfb);
    gemm_mn<false><<<dim3(576), 512, 0, stream>>>(xb, Wqb, qkvn, 1024, 1152);
    ln_row<<<dim3(4096), 64, 0, stream>>>(qkvn, gamma, beta, vT);
    attn_kernel<<<dim3(16, 32), 512, 0, stream>>>(qkvn, vT, abuf);
    gemm_mn<true><<<dim3(512), 512, 0, stream>>>(abuf, Wfb, out, 1024, 1024);
}